// Round 2
// baseline (269.598 us; speedup 1.0000x reference)
//
#include <hip/hip_runtime.h>

#define NN 20000
#define NE 480000

// float-element offsets into d_out
#define OFF_V    0
#define OFF_E    1521824
#define OFF_R    119121824
#define OFF_T    119302040
#define OFF_RTS  119362112
#define OFF_TTS  124762112
#define OFF_BAT  126562112
#define OFF_EDG  126582136
#define OFF_CHN  127782136

struct Frame { float m[3][3]; float t[3]; };

// M = Rn@Rc; reference R (already transposed) = M^T, so R^T x = M x.
__device__ __forceinline__ void make_frame(const float a0[3], const float a1[3],
                                           const float a2[3], Frame& F){
  float nlx = a0[0]-a1[0], nly = a0[1]-a1[1], nlz = a0[2]-a1[2];
  float cx  = a2[0]-a1[0], cy  = a2[1]-a1[1], cz  = a2[2]-a1[2];
  float xy2 = cx*cx + cy*cy;
  float n1 = sqrtf(1e-20f + xy2);
  float s1 = -cy/n1, c1 = cx/n1;
  float n2 = sqrtf(1e-20f + xy2 + cz*cz);
  float s2 = cz/n2, c2 = sqrtf(xy2)/n2;
  float R00 = c2*c1, R01 = -c2*s1, R02 = s2;
  float R10 = s1,    R11 = c1,     R12 = 0.f;
  float R20 = -s2*c1,R21 = s2*s1,  R22 = c2;
  float nr1 = R10*nlx + R11*nly + R12*nlz;
  float nr2 = R20*nlx + R21*nly + R22*nlz;
  float n3 = sqrtf(1e-20f + nr1*nr1 + nr2*nr2);
  float sn = -nr2/n3, cn = nr1/n3;
  F.m[0][0]=R00;              F.m[0][1]=R01;              F.m[0][2]=R02;
  F.m[1][0]=cn*R10 - sn*R20;  F.m[1][1]=cn*R11 - sn*R21;  F.m[1][2]=cn*R12 - sn*R22;
  F.m[2][0]=sn*R10 + cn*R20;  F.m[2][1]=sn*R11 + cn*R21;  F.m[2][2]=sn*R12 + cn*R22;
  F.t[0]=a1[0]; F.t[1]=a1[1]; F.t[2]=a1[2];
}

// direct(3) + rbf(16) of one 3-vector into b[0..18]
__device__ __forceinline__ void decouple19(float ux, float uy, float uz, float* b){
  float sq = ux*ux + uy*uy + uz*uz;
  float nrm = (sq == 0.f) ? 0.f : sqrtf(sq);
  float inv = 1.0f / (nrm + 1e-6f);
  b[0] = ux*inv; b[1] = uy*inv; b[2] = uz*inv;
#pragma unroll
  for (int k = 0; k < 16; k++){
    float mu = (float)k * (20.0f/15.0f);
    float z = (nrm - mu) * 0.8f;            // sigma = 1.25
    b[3+k] = __expf(-z*z);
  }
}

__global__ __launch_bounds__(256) void node_kernel(
    const float* __restrict__ X, const int* __restrict__ bat,
    const int* __restrict__ chn, float* __restrict__ out){
  int n = blockIdx.x*256 + threadIdx.x;
  if (n >= NN) return;
  const float* xp = X + (size_t)n*12;
  float a[4][3];
#pragma unroll
  for (int i = 0; i < 12; i++) a[i/3][i%3] = xp[i];
  Frame F; make_frame(a[0], a[1], a[2], F);

  float d[4][3];
  if (n > 0){ d[0][0]=a[0][0]-xp[-3]; d[0][1]=a[0][1]-xp[-2]; d[0][2]=a[0][2]-xp[-1]; }
  else      { d[0][0]=0.f; d[0][1]=0.f; d[0][2]=0.f; }
#pragma unroll
  for (int q = 1; q < 4; q++){
    d[q][0]=a[q][0]-a[q-1][0]; d[q][1]=a[q][1]-a[q-1][1]; d[q][2]=a[q][2]-a[q-1][2];
  }

  float buf[76];
#pragma unroll
  for (int q = 0; q < 4; q++){
    float vx = F.m[0][0]*d[q][0] + F.m[0][1]*d[q][1] + F.m[0][2]*d[q][2];
    float vy = F.m[1][0]*d[q][0] + F.m[1][1]*d[q][1] + F.m[1][2]*d[q][2];
    float vz = F.m[2][0]*d[q][0] + F.m[2][1]*d[q][1] + F.m[2][2]*d[q][2];
    decouple19(vx, vy, vz, buf + q*19);
  }
  float4* vrow = reinterpret_cast<float4*>(out + OFF_V + (size_t)n*76);
#pragma unroll
  for (int i = 0; i < 19; i++)
    vrow[i] = make_float4(buf[4*i], buf[4*i+1], buf[4*i+2], buf[4*i+3]);

  float* rr = out + OFF_R + (size_t)n*9;
#pragma unroll
  for (int i = 0; i < 3; i++)
#pragma unroll
    for (int j = 0; j < 3; j++) rr[3*i+j] = F.m[j][i];   // R = M^T

  float* tr = out + OFF_T + (size_t)n*3;
#pragma unroll
  for (int i = 0; i < 3; i++) tr[i] = F.t[i];

  out[OFF_BAT + n] = (float)bat[n];
  out[OFF_CHN + n] = (float)chn[n];
}

__global__ __launch_bounds__(256) void edge_kernel(
    const float* __restrict__ X, const int* __restrict__ ei,
    float* __restrict__ out){
  int e = blockIdx.x*256 + threadIdx.x;
  if (e >= NE) return;
  int src = ei[e], dst = ei[NE + e];
  float as[4][3], ad[4][3];
  const float* ps = X + (size_t)src*12;
  const float* pd = X + (size_t)dst*12;
#pragma unroll
  for (int i = 0; i < 12; i++){ as[i/3][i%3] = ps[i]; ad[i/3][i%3] = pd[i]; }
  Frame Fs, Fd;
  make_frame(as[0], as[1], as[2], Fs);
  make_frame(ad[0], ad[1], ad[2], Fd);

  float* rowE = out + OFF_E + (size_t)e*196;
  float buf[76];

  // phase 1: src atoms in src frame
#pragma unroll
  for (int q = 0; q < 4; q++){
    float y0 = as[q][0]-Fs.t[0], y1 = as[q][1]-Fs.t[1], y2 = as[q][2]-Fs.t[2];
    float vx = Fs.m[0][0]*y0 + Fs.m[0][1]*y1 + Fs.m[0][2]*y2;
    float vy = Fs.m[1][0]*y0 + Fs.m[1][1]*y1 + Fs.m[1][2]*y2;
    float vz = Fs.m[2][0]*y0 + Fs.m[2][1]*y1 + Fs.m[2][2]*y2;
    decouple19(vx, vy, vz, buf + q*19);
  }
  {
    float4* p = reinterpret_cast<float4*>(rowE);
#pragma unroll
    for (int i = 0; i < 19; i++)
      p[i] = make_float4(buf[4*i], buf[4*i+1], buf[4*i+2], buf[4*i+3]);
  }
  // phase 2: dst atoms in src frame
#pragma unroll
  for (int q = 0; q < 4; q++){
    float y0 = ad[q][0]-Fs.t[0], y1 = ad[q][1]-Fs.t[1], y2 = ad[q][2]-Fs.t[2];
    float vx = Fs.m[0][0]*y0 + Fs.m[0][1]*y1 + Fs.m[0][2]*y2;
    float vy = Fs.m[1][0]*y0 + Fs.m[1][1]*y1 + Fs.m[1][2]*y2;
    float vz = Fs.m[2][0]*y0 + Fs.m[2][1]*y1 + Fs.m[2][2]*y2;
    decouple19(vx, vy, vz, buf + q*19);
  }
  {
    float4* p = reinterpret_cast<float4*>(rowE + 76);
#pragma unroll
    for (int i = 0; i < 19; i++)
      p[i] = make_float4(buf[4*i], buf[4*i+1], buf[4*i+2], buf[4*i+3]);
  }
  // phase 3: quant(9) + trans(19) + pos_embed(16) = 44
  float rts[3][3];
#pragma unroll
  for (int i = 0; i < 3; i++)
#pragma unroll
    for (int k = 0; k < 3; k++)
      rts[i][k] = Fd.m[i][0]*Fs.m[k][0] + Fd.m[i][1]*Fs.m[k][1] + Fd.m[i][2]*Fs.m[k][2];
  float dt0 = Fs.t[0]-Fd.t[0], dt1 = Fs.t[1]-Fd.t[1], dt2 = Fs.t[2]-Fd.t[2];
  float tt[3];
#pragma unroll
  for (int i = 0; i < 3; i++) tt[i] = Fd.m[i][0]*dt0 + Fd.m[i][1]*dt1 + Fd.m[i][2]*dt2;

#pragma unroll
  for (int i = 0; i < 3; i++)
#pragma unroll
    for (int j = 0; j < 3; j++) buf[3*i+j] = rts[j][i];   // E_quant = R_ts^T
  decouple19(tt[0], tt[1], tt[2], buf + 9);
  {
    float df = (float)(src - dst);
    const float FR[8] = {1.f, 0.31622776601683794f, 0.1f, 0.031622776601683794f,
                         0.01f, 0.0031622776601683794f, 0.001f, 0.00031622776601683794f};
#pragma unroll
    for (int j = 0; j < 8; j++){
      float s, c; __sincosf(df * FR[j], &s, &c);
      buf[28+j] = c;
      buf[36+j] = s;
    }
  }
  {
    float4* p = reinterpret_cast<float4*>(rowE + 152);
#pragma unroll
    for (int i = 0; i < 11; i++)
      p[i] = make_float4(buf[4*i], buf[4*i+1], buf[4*i+2], buf[4*i+3]);
  }

  float* rr = out + OFF_RTS + (size_t)e*9;
#pragma unroll
  for (int i = 0; i < 3; i++)
#pragma unroll
    for (int k = 0; k < 3; k++) rr[3*i+k] = rts[i][k];
  float* tr = out + OFF_TTS + (size_t)e*3;
#pragma unroll
  for (int i = 0; i < 3; i++) tr[i] = tt[i];

  out[OFF_EDG + e]          = (float)src;
  out[OFF_EDG + 600000 + e] = (float)dst;
}

// one kernel for all tails/fills
__global__ __launch_bounds__(256) void fill_kernel(const int* __restrict__ bat,
                                                   float* __restrict__ out){
  int i = blockIdx.x*256 + threadIdx.x;
  // seg0: E_all tail zeros: 120000*196 floats = 5,880,000 uint4
  if (i < 5880000){
    uint4 z; z.x=0; z.y=0; z.z=0; z.w=0;
    reinterpret_cast<uint4*>(out + 95601824)[i] = z;
    return;
  }
  i -= 5880000;
  // seg1: tts tail zeros: 360000 floats = 90,000 uint4
  if (i < 90000){
    uint4 z; z.x=0; z.y=0; z.z=0; z.w=0;
    reinterpret_cast<uint4*>(out + 126202112)[i] = z;
    return;
  }
  i -= 90000;
  // seg2: Rts tail eyes: 120000*9 floats
  if (i < 1080000){
    int r = i % 9;
    out[OFF_RTS + 4320000 + i] = (r==0 || r==4 || r==8) ? 1.0f : 0.0f;
    return;
  }
  i -= 1080000;
  // seg3: global edges
  if (i < 120000){
    int v0, v1;
    if (i < 60000){ int k = i/20000, m = i - 20000*k; v0 = bat[m] + 20000 + k*8; v1 = m; }
    else { int i2 = i - 60000; int k = i2/20000, m = i2 - 20000*k; v0 = m; v1 = bat[m] + 20000 + k*8; }
    out[OFF_EDG + 480000 + i]          = (float)v0;
    out[OFF_EDG + 600000 + 480000 + i] = (float)v1;
    return;
  }
  i -= 120000;
  // seg4: small tails (2160 values)
  if (i >= 2160) return;
  if (i < 1824){                                   // V_g: int_embedding(tile(arange(3),8), 76)
    int r = i / 76, c = i % 76;
    float hv = (float)(r % 3);
    int j = (c < 38) ? c : c - 38;
    float fr = __expf(-(float)(2*j) * (9.210340371976184f/76.0f));
    float ang = hv * fr;
    out[OFF_V + 1520000 + i] = (c < 38) ? cosf(ang) : sinf(ang);
  } else if (i < 2040){                            // R_all tail: 24 eyes
    int k = i - 1824; int r = k % 9;
    out[OFF_R + 180000 + k] = (r==0 || r==4 || r==8) ? 1.0f : 0.0f;
  } else if (i < 2112){                            // t_all tail zeros
    out[OFF_T + 60000 + (i - 2040)] = 0.0f;
  } else if (i < 2136){                            // batch tail: tile(arange(8),3)
    int k = i - 2112;
    out[OFF_BAT + 20000 + k] = (float)(k % 8);
  } else {                                         // chain tail: 1001
    out[OFF_CHN + 20000 + (i - 2136)] = 1001.0f;
  }
}

extern "C" void kernel_launch(void* const* d_in, const int* in_sizes, int n_in,
                              void* d_out, int out_size, void* d_ws, size_t ws_size,
                              hipStream_t stream) {
  const float* X   = (const float*)d_in[0];
  const int* ei    = (const int*)d_in[1];
  const int* bat   = (const int*)d_in[2];
  const int* chn   = (const int*)d_in[3];
  float* out = (float*)d_out;

  node_kernel<<<(NN + 255)/256, 256, 0, stream>>>(X, bat, chn, out);
  edge_kernel<<<NE/256, 256, 0, stream>>>(X, ei, out);
  // total fill threads: 5,880,000 + 90,000 + 1,080,000 + 120,000 + 2,160 = 7,172,160
  fill_kernel<<<(7172160 + 255)/256, 256, 0, stream>>>(bat, out);
}

// Round 3
// 120.641 us; speedup vs baseline: 2.2347x; 2.2347x over previous
//
#include <hip/hip_runtime.h>

#define NN 20000
#define NE 480000

// float-element offsets into d_out
#define OFF_V    0
#define OFF_E    1521824
#define OFF_R    119121824
#define OFF_T    119302040
#define OFF_RTS  119362112
#define OFF_TTS  124762112
#define OFF_BAT  126562112
#define OFF_EDG  126582136
#define OFF_CHN  127782136

#define REC 65   // LDS record stride in floats (odd -> 2-way bank aliasing = free)

struct Frame { float m[3][3]; float t[3]; };

// M = Rn@Rc; reference R (already transposed) = M^T, so R^T x = M x.
__device__ __forceinline__ void make_frame(const float a0[3], const float a1[3],
                                           const float a2[3], Frame& F){
  float nlx = a0[0]-a1[0], nly = a0[1]-a1[1], nlz = a0[2]-a1[2];
  float cx  = a2[0]-a1[0], cy  = a2[1]-a1[1], cz  = a2[2]-a1[2];
  float xy2 = cx*cx + cy*cy;
  float n1 = sqrtf(1e-20f + xy2);
  float s1 = -cy/n1, c1 = cx/n1;
  float n2 = sqrtf(1e-20f + xy2 + cz*cz);
  float s2 = cz/n2, c2 = sqrtf(xy2)/n2;
  float R00 = c2*c1, R01 = -c2*s1, R02 = s2;
  float R10 = s1,    R11 = c1,     R12 = 0.f;
  float R20 = -s2*c1,R21 = s2*s1,  R22 = c2;
  float nr1 = R10*nlx + R11*nly + R12*nlz;
  float nr2 = R20*nlx + R21*nly + R22*nlz;
  float n3 = sqrtf(1e-20f + nr1*nr1 + nr2*nr2);
  float sn = -nr2/n3, cn = nr1/n3;
  F.m[0][0]=R00;              F.m[0][1]=R01;              F.m[0][2]=R02;
  F.m[1][0]=cn*R10 - sn*R20;  F.m[1][1]=cn*R11 - sn*R21;  F.m[1][2]=cn*R12 - sn*R22;
  F.m[2][0]=sn*R10 + cn*R20;  F.m[2][1]=sn*R11 + cn*R21;  F.m[2][2]=sn*R12 + cn*R22;
  F.t[0]=a1[0]; F.t[1]=a1[1]; F.t[2]=a1[2];
}

// (dir3, nrm) of one vector into rec[off..off+3]
__device__ __forceinline__ void group4(float ux, float uy, float uz, float* rec, int off){
  float sq = ux*ux + uy*uy + uz*uz;
  float nrm = (sq == 0.f) ? 0.f : sqrtf(sq);
  float inv = 1.0f / (nrm + 1e-6f);
  rec[off+0] = ux*inv; rec[off+1] = uy*inv; rec[off+2] = uz*inv; rec[off+3] = nrm;
}

__global__ __launch_bounds__(128) void edge_kernel(
    const float* __restrict__ X, const int* __restrict__ ei,
    float* __restrict__ out){
  __shared__ float lds[2*64*REC];
  const int tid  = threadIdx.x;
  const int lane = tid & 63;
  const int wave = tid >> 6;
  const int e_my = blockIdx.x*128 + tid;     // grid is exact: 3750*128 = NE

  // ---------------- stage 1: per-thread edge record ----------------
  int src = ei[e_my], dst = ei[NE + e_my];
  const float* ps = X + (size_t)src*12;
  const float* pd = X + (size_t)dst*12;
  float as[4][3], ad[4][3];
#pragma unroll
  for (int i = 0; i < 12; i++){ as[i/3][i%3] = ps[i]; ad[i/3][i%3] = pd[i]; }
  Frame Fs, Fd;
  make_frame(as[0], as[1], as[2], Fs);
  make_frame(ad[0], ad[1], ad[2], Fd);

  float* rec = lds + (wave*64 + lane)*REC;

  // groups 0..3: src atoms, 4..7: dst atoms (all in src frame)
#pragma unroll
  for (int q = 0; q < 4; q++){
    float y0 = as[q][0]-Fs.t[0], y1 = as[q][1]-Fs.t[1], y2 = as[q][2]-Fs.t[2];
    group4(Fs.m[0][0]*y0 + Fs.m[0][1]*y1 + Fs.m[0][2]*y2,
           Fs.m[1][0]*y0 + Fs.m[1][1]*y1 + Fs.m[1][2]*y2,
           Fs.m[2][0]*y0 + Fs.m[2][1]*y1 + Fs.m[2][2]*y2, rec, 4*q);
  }
#pragma unroll
  for (int q = 0; q < 4; q++){
    float y0 = ad[q][0]-Fs.t[0], y1 = ad[q][1]-Fs.t[1], y2 = ad[q][2]-Fs.t[2];
    group4(Fs.m[0][0]*y0 + Fs.m[0][1]*y1 + Fs.m[0][2]*y2,
           Fs.m[1][0]*y0 + Fs.m[1][1]*y1 + Fs.m[1][2]*y2,
           Fs.m[2][0]*y0 + Fs.m[2][1]*y1 + Fs.m[2][2]*y2, rec, 16 + 4*q);
  }
  // rts[i][k] = dot(Md[i], Ms[k]) at rec[36+3i+k]
#pragma unroll
  for (int i = 0; i < 3; i++)
#pragma unroll
    for (int k = 0; k < 3; k++)
      rec[36+3*i+k] = Fd.m[i][0]*Fs.m[k][0] + Fd.m[i][1]*Fs.m[k][1] + Fd.m[i][2]*Fs.m[k][2];
  // tt = Md (ts - td)  at rec[45..47]; group 8 (dir,nrm of tt) at rec[32..35]
  {
    float d0 = Fs.t[0]-Fd.t[0], d1 = Fs.t[1]-Fd.t[1], d2 = Fs.t[2]-Fd.t[2];
    float t0 = Fd.m[0][0]*d0 + Fd.m[0][1]*d1 + Fd.m[0][2]*d2;
    float t1 = Fd.m[1][0]*d0 + Fd.m[1][1]*d1 + Fd.m[1][2]*d2;
    float t2 = Fd.m[2][0]*d0 + Fd.m[2][1]*d1 + Fd.m[2][2]*d2;
    rec[45] = t0; rec[46] = t1; rec[47] = t2;
    group4(t0, t1, t2, rec, 32);
  }
  // pos embed: cos at rec[48+k], sin at rec[56+k]
  {
    float df = (float)(src - dst);
    const float FR[8] = {1.f, 0.31622776601683794f, 0.1f, 0.031622776601683794f,
                         0.01f, 0.0031622776601683794f, 0.001f, 0.00031622776601683794f};
#pragma unroll
    for (int k = 0; k < 8; k++){
      float s, c; __sincosf(df * FR[k], &s, &c);
      rec[48+k] = c; rec[56+k] = s;
    }
  }
  // edge-index outputs (coalesced across the wave)
  out[OFF_EDG + e_my]          = (float)src;
  out[OFF_EDG + 600000 + e_my] = (float)dst;

  __syncthreads();

  // ---------------- stage 2: wave writes 64 rows coalesced ----------------
  // per-lane element table: elements j = 4*lane + c of the 196-float row
  int   offb[4];
  float msk[4], mu[4];
#pragma unroll
  for (int c = 0; c < 4; c++){
    int j = 4*lane + c;
    int off = 0; float m = 0.f, rm = 0.f;
    if (j < 152){
      int jj = (j < 76) ? j : j - 76;
      int g  = ((j < 76) ? 0 : 4) + jj/19;
      int r  = jj - 19*(jj/19);
      if (r < 3) off = 4*g + r;
      else { off = 4*g + 3; m = 1.f; rm = (float)(r-3) * (20.0f/15.0f); }
    } else if (j < 161){
      int q = j - 152;                         // E_quant[m] = rts[m%3][m/3]
      off = 36 + 3*(q - 3*(q/3)) + q/3;
    } else if (j < 180){
      int r = j - 161;
      if (r < 3) off = 32 + r;
      else { off = 35; m = 1.f; rm = (float)(r-3) * (20.0f/15.0f); }
    } else if (j < 196){
      off = 48 + (j - 180);
    } else {
      off = 0;                                  // lanes 49..63: harmless read
    }
    offb[c] = off; msk[c] = m; mu[c] = rm;
  }

  const float* wlds = lds + wave*64*REC;
  const int wave_ebase = blockIdx.x*128 + wave*64;
  float4* pstore = reinterpret_cast<float4*>(out + OFF_E + (size_t)wave_ebase*196) + lane;

#pragma unroll 2
  for (int e = 0; e < 64; e++){
    const float* r = wlds + e*REC;
    float v[4];
#pragma unroll
    for (int c = 0; c < 4; c++){
      float x  = r[offb[c]];
      float z  = (x - mu[c]) * 0.8f;            // sigma = 1.25
      float rv = __expf(-z*z);
      v[c] = fmaf(msk[c], rv - x, x);           // select: rbf or passthrough
    }
    if (lane < 49)
      *pstore = make_float4(v[0], v[1], v[2], v[3]);
    pstore += 49;
  }

  // RTS rows: 64 edges x 9 floats, fully coalesced (addr = base + k*64 + lane)
#pragma unroll
  for (int k = 0; k < 9; k++){
    int f = k*64 + lane;
    int e = f/9, m = f - 9*e;
    out[OFF_RTS + (size_t)wave_ebase*9 + f] = wlds[e*REC + 36 + m];
  }
  // TTS rows: 64 x 3
#pragma unroll
  for (int k = 0; k < 3; k++){
    int f = k*64 + lane;
    int e = f/3, m = f - 3*e;
    out[OFF_TTS + (size_t)wave_ebase*3 + f] = wlds[e*REC + 45 + m];
  }
}

// direct(3) + rbf(16) of one 3-vector into b[0..18]
__device__ __forceinline__ void decouple19(float ux, float uy, float uz, float* b){
  float sq = ux*ux + uy*uy + uz*uz;
  float nrm = (sq == 0.f) ? 0.f : sqrtf(sq);
  float inv = 1.0f / (nrm + 1e-6f);
  b[0] = ux*inv; b[1] = uy*inv; b[2] = uz*inv;
#pragma unroll
  for (int k = 0; k < 16; k++){
    float mu = (float)k * (20.0f/15.0f);
    float z = (nrm - mu) * 0.8f;
    b[3+k] = __expf(-z*z);
  }
}

__global__ __launch_bounds__(256) void node_kernel(
    const float* __restrict__ X, const int* __restrict__ bat,
    const int* __restrict__ chn, float* __restrict__ out){
  int n = blockIdx.x*256 + threadIdx.x;
  if (n >= NN) return;
  const float* xp = X + (size_t)n*12;
  float a[4][3];
#pragma unroll
  for (int i = 0; i < 12; i++) a[i/3][i%3] = xp[i];
  Frame F; make_frame(a[0], a[1], a[2], F);

  float d[4][3];
  if (n > 0){ d[0][0]=a[0][0]-xp[-3]; d[0][1]=a[0][1]-xp[-2]; d[0][2]=a[0][2]-xp[-1]; }
  else      { d[0][0]=0.f; d[0][1]=0.f; d[0][2]=0.f; }
#pragma unroll
  for (int q = 1; q < 4; q++){
    d[q][0]=a[q][0]-a[q-1][0]; d[q][1]=a[q][1]-a[q-1][1]; d[q][2]=a[q][2]-a[q-1][2];
  }

  float buf[76];
#pragma unroll
  for (int q = 0; q < 4; q++){
    float vx = F.m[0][0]*d[q][0] + F.m[0][1]*d[q][1] + F.m[0][2]*d[q][2];
    float vy = F.m[1][0]*d[q][0] + F.m[1][1]*d[q][1] + F.m[1][2]*d[q][2];
    float vz = F.m[2][0]*d[q][0] + F.m[2][1]*d[q][1] + F.m[2][2]*d[q][2];
    decouple19(vx, vy, vz, buf + q*19);
  }
  float4* vrow = reinterpret_cast<float4*>(out + OFF_V + (size_t)n*76);
#pragma unroll
  for (int i = 0; i < 19; i++)
    vrow[i] = make_float4(buf[4*i], buf[4*i+1], buf[4*i+2], buf[4*i+3]);

  float* rr = out + OFF_R + (size_t)n*9;
#pragma unroll
  for (int i = 0; i < 3; i++)
#pragma unroll
    for (int j = 0; j < 3; j++) rr[3*i+j] = F.m[j][i];   // R = M^T

  float* tr = out + OFF_T + (size_t)n*3;
#pragma unroll
  for (int i = 0; i < 3; i++) tr[i] = F.t[i];

  out[OFF_BAT + n] = (float)bat[n];
  out[OFF_CHN + n] = (float)chn[n];
}

// one kernel for all tails/fills
__global__ __launch_bounds__(256) void fill_kernel(const int* __restrict__ bat,
                                                   float* __restrict__ out){
  int i = blockIdx.x*256 + threadIdx.x;
  // seg0: E_all tail zeros: 120000*196 floats = 5,880,000 uint4
  if (i < 5880000){
    uint4 z; z.x=0; z.y=0; z.z=0; z.w=0;
    reinterpret_cast<uint4*>(out + 95601824)[i] = z;
    return;
  }
  i -= 5880000;
  // seg1: tts tail zeros: 360000 floats = 90,000 uint4
  if (i < 90000){
    uint4 z; z.x=0; z.y=0; z.z=0; z.w=0;
    reinterpret_cast<uint4*>(out + 126202112)[i] = z;
    return;
  }
  i -= 90000;
  // seg2: Rts tail eyes: 120000*9 floats
  if (i < 1080000){
    int r = i % 9;
    out[OFF_RTS + 4320000 + i] = (r==0 || r==4 || r==8) ? 1.0f : 0.0f;
    return;
  }
  i -= 1080000;
  // seg3: global edges
  if (i < 120000){
    int v0, v1;
    if (i < 60000){ int k = i/20000, m = i - 20000*k; v0 = bat[m] + 20000 + k*8; v1 = m; }
    else { int i2 = i - 60000; int k = i2/20000, m = i2 - 20000*k; v0 = m; v1 = bat[m] + 20000 + k*8; }
    out[OFF_EDG + 480000 + i]          = (float)v0;
    out[OFF_EDG + 600000 + 480000 + i] = (float)v1;
    return;
  }
  i -= 120000;
  // seg4: small tails (2160 values)
  if (i >= 2160) return;
  if (i < 1824){                                   // V_g: int_embedding(tile(arange(3),8), 76)
    int r = i / 76, c = i % 76;
    float hv = (float)(r % 3);
    int j = (c < 38) ? c : c - 38;
    float fr = __expf(-(float)(2*j) * (9.210340371976184f/76.0f));
    float ang = hv * fr;
    out[OFF_V + 1520000 + i] = (c < 38) ? cosf(ang) : sinf(ang);
  } else if (i < 2040){                            // R_all tail: 24 eyes
    int k = i - 1824; int r = k % 9;
    out[OFF_R + 180000 + k] = (r==0 || r==4 || r==8) ? 1.0f : 0.0f;
  } else if (i < 2112){                            // t_all tail zeros
    out[OFF_T + 60000 + (i - 2040)] = 0.0f;
  } else if (i < 2136){                            // batch tail: tile(arange(8),3)
    int k = i - 2112;
    out[OFF_BAT + 20000 + k] = (float)(k % 8);
  } else {                                         // chain tail: 1001
    out[OFF_CHN + 20000 + (i - 2136)] = 1001.0f;
  }
}

extern "C" void kernel_launch(void* const* d_in, const int* in_sizes, int n_in,
                              void* d_out, int out_size, void* d_ws, size_t ws_size,
                              hipStream_t stream) {
  const float* X   = (const float*)d_in[0];
  const int* ei    = (const int*)d_in[1];
  const int* bat   = (const int*)d_in[2];
  const int* chn   = (const int*)d_in[3];
  float* out = (float*)d_out;

  node_kernel<<<(NN + 255)/256, 256, 0, stream>>>(X, bat, chn, out);
  edge_kernel<<<NE/128, 128, 0, stream>>>(X, ei, out);
  fill_kernel<<<(7172160 + 255)/256, 256, 0, stream>>>(bat, out);
}

// Round 4
// 114.946 us; speedup vs baseline: 2.3454x; 1.0495x over previous
//
#include <hip/hip_runtime.h>

#define NN 20000
#define NE 480000

// float-element offsets into d_out
#define OFF_V    0
#define OFF_E    1521824
#define OFF_R    119121824
#define OFF_T    119302040
#define OFF_RTS  119362112
#define OFF_TTS  124762112
#define OFF_BAT  126562112
#define OFF_EDG  126582136
#define OFF_CHN  127782136

#define REC 65   // LDS record stride in floats (odd -> conflict-free stage-1 writes)

// block-range dispatch
#define NB_EDGE 3750                 // 3750 blocks * 128 thr = 480000 edges
#define NB_NODE 157                  // 157 * 128 >= 20000
#define NB_FILL 26385                // ceil(3,377,160 / 128)
#define NB_TOTAL (NB_EDGE + NB_NODE + NB_FILL)

struct Frame { float m[3][3]; float t[3]; };

// M = Rn@Rc; reference R (already transposed) = M^T, so R^T x = M x.
__device__ __forceinline__ void make_frame(const float a0[3], const float a1[3],
                                           const float a2[3], Frame& F){
  float nlx = a0[0]-a1[0], nly = a0[1]-a1[1], nlz = a0[2]-a1[2];
  float cx  = a2[0]-a1[0], cy  = a2[1]-a1[1], cz  = a2[2]-a1[2];
  float xy2 = cx*cx + cy*cy;
  float n1 = sqrtf(1e-20f + xy2);
  float s1 = -cy/n1, c1 = cx/n1;
  float n2 = sqrtf(1e-20f + xy2 + cz*cz);
  float s2 = cz/n2, c2 = sqrtf(xy2)/n2;
  float R00 = c2*c1, R01 = -c2*s1, R02 = s2;
  float R10 = s1,    R11 = c1,     R12 = 0.f;
  float R20 = -s2*c1,R21 = s2*s1,  R22 = c2;
  float nr1 = R10*nlx + R11*nly + R12*nlz;
  float nr2 = R20*nlx + R21*nly + R22*nlz;
  float n3 = sqrtf(1e-20f + nr1*nr1 + nr2*nr2);
  float sn = -nr2/n3, cn = nr1/n3;
  F.m[0][0]=R00;              F.m[0][1]=R01;              F.m[0][2]=R02;
  F.m[1][0]=cn*R10 - sn*R20;  F.m[1][1]=cn*R11 - sn*R21;  F.m[1][2]=cn*R12 - sn*R22;
  F.m[2][0]=sn*R10 + cn*R20;  F.m[2][1]=sn*R11 + cn*R21;  F.m[2][2]=sn*R12 + cn*R22;
  F.t[0]=a1[0]; F.t[1]=a1[1]; F.t[2]=a1[2];
}

// (dir3, nrm) of one vector into rec[off..off+3]
__device__ __forceinline__ void group4(float ux, float uy, float uz, float* rec, int off){
  float sq = ux*ux + uy*uy + uz*uz;
  float nrm = (sq == 0.f) ? 0.f : sqrtf(sq);
  float inv = 1.0f / (nrm + 1e-6f);
  rec[off+0] = ux*inv; rec[off+1] = uy*inv; rec[off+2] = uz*inv; rec[off+3] = nrm;
}

// direct(3) + rbf(16) of one 3-vector into b[0..18]
__device__ __forceinline__ void decouple19(float ux, float uy, float uz, float* b){
  float sq = ux*ux + uy*uy + uz*uz;
  float nrm = (sq == 0.f) ? 0.f : sqrtf(sq);
  float inv = 1.0f / (nrm + 1e-6f);
  b[0] = ux*inv; b[1] = uy*inv; b[2] = uz*inv;
#pragma unroll
  for (int k = 0; k < 16; k++){
    float mu = (float)k * (20.0f/15.0f);
    float z = (nrm - mu) * 0.8f;
    b[3+k] = __expf(-z*z);
  }
}

__global__ __launch_bounds__(128) void mega_kernel(
    const float* __restrict__ X, const int* __restrict__ ei,
    const int* __restrict__ bat, const int* __restrict__ chn,
    float* __restrict__ out){
  __shared__ float lds[2*64*REC];
  const int blk = blockIdx.x;
  const int tid = threadIdx.x;

  if (blk < NB_EDGE){
    // ======================= EDGE PATH (2 independent waves) ================
    const int lane = tid & 63;
    const int wave = tid >> 6;
    const int e_my = blk*128 + tid;

    // ------- stage 1: per-thread edge record into this wave's LDS half -----
    int src = ei[e_my], dst = ei[NE + e_my];
    const float* ps = X + (size_t)src*12;
    const float* pd = X + (size_t)dst*12;
    float as[4][3], ad[4][3];
#pragma unroll
    for (int i = 0; i < 12; i++){ as[i/3][i%3] = ps[i]; ad[i/3][i%3] = pd[i]; }
    Frame Fs, Fd;
    make_frame(as[0], as[1], as[2], Fs);
    make_frame(ad[0], ad[1], ad[2], Fd);

    float* rec = lds + (wave*64 + lane)*REC;

#pragma unroll
    for (int q = 0; q < 4; q++){
      float y0 = as[q][0]-Fs.t[0], y1 = as[q][1]-Fs.t[1], y2 = as[q][2]-Fs.t[2];
      group4(Fs.m[0][0]*y0 + Fs.m[0][1]*y1 + Fs.m[0][2]*y2,
             Fs.m[1][0]*y0 + Fs.m[1][1]*y1 + Fs.m[1][2]*y2,
             Fs.m[2][0]*y0 + Fs.m[2][1]*y1 + Fs.m[2][2]*y2, rec, 4*q);
    }
#pragma unroll
    for (int q = 0; q < 4; q++){
      float y0 = ad[q][0]-Fs.t[0], y1 = ad[q][1]-Fs.t[1], y2 = ad[q][2]-Fs.t[2];
      group4(Fs.m[0][0]*y0 + Fs.m[0][1]*y1 + Fs.m[0][2]*y2,
             Fs.m[1][0]*y0 + Fs.m[1][1]*y1 + Fs.m[1][2]*y2,
             Fs.m[2][0]*y0 + Fs.m[2][1]*y1 + Fs.m[2][2]*y2, rec, 16 + 4*q);
    }
#pragma unroll
    for (int i = 0; i < 3; i++)
#pragma unroll
      for (int k = 0; k < 3; k++)
        rec[36+3*i+k] = Fd.m[i][0]*Fs.m[k][0] + Fd.m[i][1]*Fs.m[k][1] + Fd.m[i][2]*Fs.m[k][2];
    {
      float d0 = Fs.t[0]-Fd.t[0], d1 = Fs.t[1]-Fd.t[1], d2 = Fs.t[2]-Fd.t[2];
      float t0 = Fd.m[0][0]*d0 + Fd.m[0][1]*d1 + Fd.m[0][2]*d2;
      float t1 = Fd.m[1][0]*d0 + Fd.m[1][1]*d1 + Fd.m[1][2]*d2;
      float t2 = Fd.m[2][0]*d0 + Fd.m[2][1]*d1 + Fd.m[2][2]*d2;
      rec[45] = t0; rec[46] = t1; rec[47] = t2;
      group4(t0, t1, t2, rec, 32);
    }
    {
      float df = (float)(src - dst);
      const float FR[8] = {1.f, 0.31622776601683794f, 0.1f, 0.031622776601683794f,
                           0.01f, 0.0031622776601683794f, 0.001f, 0.00031622776601683794f};
#pragma unroll
      for (int k = 0; k < 8; k++){
        float s, c; __sincosf(df * FR[k], &s, &c);
        rec[48+k] = c; rec[56+k] = s;
      }
    }
    out[OFF_EDG + e_my]          = (float)src;
    out[OFF_EDG + 600000 + e_my] = (float)dst;

    // no barrier: stage 2 reads only this wave's LDS half (wave-synchronous)

    // ------- stage 2: wave writes its 64 rows coalesced --------------------
    int   offb[4];
    float msk[4], mu[4];
#pragma unroll
    for (int c = 0; c < 4; c++){
      int j = 4*lane + c;
      int off = 0; float m = 0.f, rm = 0.f;
      if (j < 152){
        int jj = (j < 76) ? j : j - 76;
        int g  = ((j < 76) ? 0 : 4) + jj/19;
        int r  = jj - 19*(jj/19);
        if (r < 3) off = 4*g + r;
        else { off = 4*g + 3; m = 1.f; rm = (float)(r-3) * (20.0f/15.0f); }
      } else if (j < 161){
        int q = j - 152;                         // E_quant[m] = rts[m%3][m/3]
        off = 36 + 3*(q - 3*(q/3)) + q/3;
      } else if (j < 180){
        int r = j - 161;
        if (r < 3) off = 32 + r;
        else { off = 35; m = 1.f; rm = (float)(r-3) * (20.0f/15.0f); }
      } else if (j < 196){
        off = 48 + (j - 180);
      } else {
        off = 0;
      }
      offb[c] = off; msk[c] = m; mu[c] = rm;
    }

    const float* wlds = lds + wave*64*REC;
    const int wave_ebase = blk*128 + wave*64;
    float4* pstore = reinterpret_cast<float4*>(out + OFF_E + (size_t)wave_ebase*196) + lane;

#pragma unroll 2
    for (int e = 0; e < 64; e++){
      const float* r = wlds + e*REC;
      float v[4];
#pragma unroll
      for (int c = 0; c < 4; c++){
        float x  = r[offb[c]];
        float z  = (x - mu[c]) * 0.8f;          // sigma = 1.25
        float rv = __expf(-z*z);
        v[c] = fmaf(msk[c], rv - x, x);
      }
      if (lane < 49)
        *pstore = make_float4(v[0], v[1], v[2], v[3]);
      pstore += 49;
    }

#pragma unroll
    for (int k = 0; k < 9; k++){
      int f = k*64 + lane;
      int e = f/9, m = f - 9*e;
      out[OFF_RTS + (size_t)wave_ebase*9 + f] = wlds[e*REC + 36 + m];
    }
#pragma unroll
    for (int k = 0; k < 3; k++){
      int f = k*64 + lane;
      int e = f/3, m = f - 3*e;
      out[OFF_TTS + (size_t)wave_ebase*3 + f] = wlds[e*REC + 45 + m];
    }
    return;
  }

  if (blk < NB_EDGE + NB_NODE){
    // ============================ NODE PATH ================================
    int n = (blk - NB_EDGE)*128 + tid;
    if (n >= NN) return;
    const float* xp = X + (size_t)n*12;
    float a[4][3];
#pragma unroll
    for (int i = 0; i < 12; i++) a[i/3][i%3] = xp[i];
    Frame F; make_frame(a[0], a[1], a[2], F);

    float d[4][3];
    if (n > 0){ d[0][0]=a[0][0]-xp[-3]; d[0][1]=a[0][1]-xp[-2]; d[0][2]=a[0][2]-xp[-1]; }
    else      { d[0][0]=0.f; d[0][1]=0.f; d[0][2]=0.f; }
#pragma unroll
    for (int q = 1; q < 4; q++){
      d[q][0]=a[q][0]-a[q-1][0]; d[q][1]=a[q][1]-a[q-1][1]; d[q][2]=a[q][2]-a[q-1][2];
    }

    float buf[76];
#pragma unroll
    for (int q = 0; q < 4; q++){
      float vx = F.m[0][0]*d[q][0] + F.m[0][1]*d[q][1] + F.m[0][2]*d[q][2];
      float vy = F.m[1][0]*d[q][0] + F.m[1][1]*d[q][1] + F.m[1][2]*d[q][2];
      float vz = F.m[2][0]*d[q][0] + F.m[2][1]*d[q][1] + F.m[2][2]*d[q][2];
      decouple19(vx, vy, vz, buf + q*19);
    }
    float4* vrow = reinterpret_cast<float4*>(out + OFF_V + (size_t)n*76);
#pragma unroll
    for (int i = 0; i < 19; i++)
      vrow[i] = make_float4(buf[4*i], buf[4*i+1], buf[4*i+2], buf[4*i+3]);

    float* rr = out + OFF_R + (size_t)n*9;
#pragma unroll
    for (int i = 0; i < 3; i++)
#pragma unroll
      for (int j = 0; j < 3; j++) rr[3*i+j] = F.m[j][i];   // R = M^T

    float* tr = out + OFF_T + (size_t)n*3;
#pragma unroll
    for (int i = 0; i < 3; i++) tr[i] = F.t[i];

    out[OFF_BAT + n] = (float)bat[n];
    out[OFF_CHN + n] = (float)chn[n];
    return;
  }

  // ============================== FILL PATH ================================
  int i = (blk - NB_EDGE - NB_NODE)*128 + tid;
  // seg0: E_all tail zeros, 32B per thread: 2,940,000 threads
  if (i < 2940000){
    uint4 z; z.x=0; z.y=0; z.z=0; z.w=0;
    uint4* p = reinterpret_cast<uint4*>(out + 95601824) + 2*(size_t)i;
    p[0] = z; p[1] = z;
    return;
  }
  i -= 2940000;
  // seg1: tts tail zeros, 32B per thread: 45,000 threads
  if (i < 45000){
    uint4 z; z.x=0; z.y=0; z.z=0; z.w=0;
    uint4* p = reinterpret_cast<uint4*>(out + 126202112) + 2*(size_t)i;
    p[0] = z; p[1] = z;
    return;
  }
  i -= 45000;
  // seg2: Rts tail eyes, float4 per thread: 270,000 threads
  if (i < 270000){
    float v[4];
#pragma unroll
    for (int c = 0; c < 4; c++){
      int idx = 4*i + c;
      int r = idx % 9;
      v[c] = (r==0 || r==4 || r==8) ? 1.0f : 0.0f;
    }
    reinterpret_cast<float4*>(out + OFF_RTS + 4320000)[i] = make_float4(v[0],v[1],v[2],v[3]);
    return;
  }
  i -= 270000;
  // seg3: global edges: 120,000 threads
  if (i < 120000){
    int v0, v1;
    if (i < 60000){ int k = i/20000, m = i - 20000*k; v0 = bat[m] + 20000 + k*8; v1 = m; }
    else { int i2 = i - 60000; int k = i2/20000, m = i2 - 20000*k; v0 = m; v1 = bat[m] + 20000 + k*8; }
    out[OFF_EDG + 480000 + i]          = (float)v0;
    out[OFF_EDG + 600000 + 480000 + i] = (float)v1;
    return;
  }
  i -= 120000;
  // seg4: small tails (2160 values)
  if (i >= 2160) return;
  if (i < 1824){                                   // V_g: int_embedding(tile(arange(3),8), 76)
    int r = i / 76, c = i % 76;
    float hv = (float)(r % 3);
    int j = (c < 38) ? c : c - 38;
    float fr = __expf(-(float)(2*j) * (9.210340371976184f/76.0f));
    float ang = hv * fr;
    out[OFF_V + 1520000 + i] = (c < 38) ? cosf(ang) : sinf(ang);
  } else if (i < 2040){                            // R_all tail: 24 eyes
    int k = i - 1824; int r = k % 9;
    out[OFF_R + 180000 + k] = (r==0 || r==4 || r==8) ? 1.0f : 0.0f;
  } else if (i < 2112){                            // t_all tail zeros
    out[OFF_T + 60000 + (i - 2040)] = 0.0f;
  } else if (i < 2136){                            // batch tail: tile(arange(8),3)
    int k = i - 2112;
    out[OFF_BAT + 20000 + k] = (float)(k % 8);
  } else {                                         // chain tail: 1001
    out[OFF_CHN + 20000 + (i - 2136)] = 1001.0f;
  }
}

extern "C" void kernel_launch(void* const* d_in, const int* in_sizes, int n_in,
                              void* d_out, int out_size, void* d_ws, size_t ws_size,
                              hipStream_t stream) {
  const float* X   = (const float*)d_in[0];
  const int* ei    = (const int*)d_in[1];
  const int* bat   = (const int*)d_in[2];
  const int* chn   = (const int*)d_in[3];
  float* out = (float*)d_out;

  mega_kernel<<<NB_TOTAL, 128, 0, stream>>>(X, ei, bat, chn, out);
}